// Round 1
// baseline (7275.844 us; speedup 1.0000x reference)
//
#include <hip/hip_runtime.h>

typedef unsigned short u16;
typedef short v8s __attribute__((ext_vector_type(8)));
typedef float v4f __attribute__((ext_vector_type(4)));

#define Bb 256
#define Tt 512
#define Dd 64
#define Hh 512
#define G4 2048

#define NGROUP 4
#define NCHUNK 32
#define BT 64
#define HC 16
#define NCOL 64

#define WHH_S 520   // 512 + 8 pad (bf16 elems)
#define WIH_S 72    // 64 + 8 pad
#define GAT_S 68    // 64 + 4 pad (fp32 elems)
#define SMEM_BYTES (NCOL*WHH_S*2 + NCOL*WIH_S*2 + NCOL*GAT_S*4)  // 93184

#define MFMA(a,b,c) __builtin_amdgcn_mfma_f32_16x16x32_bf16((a),(b),(c),0,0,0)

__device__ __forceinline__ u16 f2bf(float f) {
  unsigned u = __float_as_uint(f);
  unsigned r = (u + 0x7fffu + ((u >> 16) & 1u)) >> 16;
  return (u16)r;
}
__device__ __forceinline__ float bf2f(u16 v) {
  return __uint_as_float(((unsigned)v) << 16);
}
__device__ __forceinline__ float sigm(float x) { return 1.0f / (1.0f + __expf(-x)); }
__device__ __forceinline__ float tanh_f(float x) {
  float a = fabsf(x);
  float e = __expf(-2.0f * a);
  float r = (1.0f - e) / (1.0f + e);
  return copysignf(r, x);
}
__device__ __forceinline__ float softplus_f(float x) { return log1pf(__expf(x)); }

// ---------------------------------------------------------------- prep:
// x fp32 [B][T][D] -> bf16 [T][B][D]; zero sync flags.
__global__ void k_prep(const float* __restrict__ x, u16* __restrict__ x_bf,
                       unsigned* __restrict__ flags)
{
  if (blockIdx.x == 0 && threadIdx.x < NGROUP * NCHUNK) flags[threadIdx.x] = 0u;
  const int N4 = Tt * Bb * Dd / 4;
  int stride = gridDim.x * blockDim.x;
  for (int i = blockIdx.x * blockDim.x + threadIdx.x; i < N4; i += stride) {
    int idx = i * 4;
    int t = idx >> 14;          // / (B*D)
    int rem = idx & 16383;
    int b = rem >> 6;
    int d = rem & 63;
    float4 v = *(const float4*)(x + (size_t)b * (Tt * Dd) + t * Dd + d);
    unsigned lo = (unsigned)f2bf(v.x) | ((unsigned)f2bf(v.y) << 16);
    unsigned hi = (unsigned)f2bf(v.z) | ((unsigned)f2bf(v.w) << 16);
    *(uint2*)(x_bf + idx) = make_uint2(lo, hi);
  }
}

// ---------------------------------------------------------------- main:
// persistent LSTM. grid = 128 blocks (4 batch groups x 32 hidden chunks),
// 256 threads. w_hh/w_ih chunk sampled into LDS once; 512 steps with
// flag-based producer/consumer sync per batch group.
__global__ __launch_bounds__(256, 1) void lstm_main(
    const float* __restrict__ whh_mu, const float* __restrict__ whh_rho, const float* __restrict__ whh_eps,
    const float* __restrict__ wih_mu, const float* __restrict__ wih_rho, const float* __restrict__ wih_eps,
    const float* __restrict__ b_mu,  const float* __restrict__ b_rho,  const float* __restrict__ b_eps,
    const u16* __restrict__ x_bf, u16* __restrict__ h_buf, unsigned* __restrict__ flags)
{
  extern __shared__ char smem[];
  u16*   w_hh_lds = (u16*)smem;                       // [NCOL][WHH_S]
  u16*   w_ih_lds = w_hh_lds + NCOL * WHH_S;          // [NCOL][WIH_S]
  float* gates    = (float*)(w_ih_lds + NCOL * WIH_S);// [NCOL][GAT_S]

  const int tid   = threadIdx.x;
  const int g     = blockIdx.x & 3;    // batch group
  const int chunk = blockIdx.x >> 2;   // hidden chunk
  const int b0    = g * BT;
  const int j0    = chunk * HC;

  // ---- sample weight chunk into LDS (bf16). local col lc = gate*16 + jj
  {
    const int lc = tid & 63;
    const int gcol = (lc >> 4) * Hh + j0 + (lc & 15);  // global gate column
    for (int k = tid >> 6; k < Hh; k += 4) {
      int gi = k * G4 + gcol;
      float w = whh_mu[gi] + softplus_f(whh_rho[gi]) * whh_eps[gi];
      w_hh_lds[lc * WHH_S + k] = f2bf(w);
    }
    for (int k = tid >> 6; k < Dd; k += 4) {
      int gi = k * G4 + gcol;
      float w = wih_mu[gi] + softplus_f(wih_rho[gi]) * wih_eps[gi];
      w_ih_lds[lc * WIH_S + k] = f2bf(w);
    }
  }

  // ---- per-thread bias (c-update stage): thread owns (jj, 4 batches)
  const int jj = tid >> 4;
  const int b4 = (tid & 15) << 2;
  float bias[4];
  #pragma unroll
  for (int gt = 0; gt < 4; ++gt) {
    int colg = gt * Hh + j0 + jj;
    bias[gt] = b_mu[colg] + softplus_f(b_rho[colg]) * b_eps[colg];
  }
  __syncthreads();

  // ---- MFMA geometry: 4 waves tile the 64x64 gate tile as 2x2 of 32x32
  const int lane = tid & 63;
  const int wv   = tid >> 6;
  const int wm0  = (wv & 1) * 32;
  const int wn0  = (wv >> 1) * 32;
  const int lm   = lane & 15;
  const int ko   = (lane >> 4) * 8;

  const u16* Bh0 = w_hh_lds + (wn0 + lm) * WHH_S + ko;
  const u16* Bh1 = Bh0 + 16 * WHH_S;
  const u16* Bx0 = w_ih_lds + (wn0 + lm) * WIH_S + ko;
  const u16* Bx1 = Bx0 + 16 * WIH_S;

  const int arow = b0 + wm0 + lm;   // A-fragment row in global h / x

  float cc0 = 0.f, cc1 = 0.f, cc2 = 0.f, cc3 = 0.f;   // persistent cell state
  const int fbase = g * NCHUNK;

  for (int t = 0; t < Tt; ++t) {
    // ---- wait until all chunks of this group published h_t
    if (t > 0) {
      if (tid < NCHUNK) {
        while (__hip_atomic_load(&flags[fbase + tid], __ATOMIC_RELAXED,
                                 __HIP_MEMORY_SCOPE_AGENT) < (unsigned)t) {
          __builtin_amdgcn_s_sleep(1);
        }
      }
      __syncthreads();
      __builtin_amdgcn_fence(__ATOMIC_ACQUIRE, "agent");
    }

    v4f a00 = {0.f, 0.f, 0.f, 0.f};
    v4f a01 = {0.f, 0.f, 0.f, 0.f};
    v4f a10 = {0.f, 0.f, 0.f, 0.f};
    v4f a11 = {0.f, 0.f, 0.f, 0.f};

    // ---- input projection: K = 64
    {
      const u16* xa = x_bf + (size_t)t * (Bb * Dd) + arow * Dd + ko;
      #pragma unroll
      for (int ks = 0; ks < 2; ++ks) {
        v8s a0 = *(const v8s*)(xa + ks * 32);
        v8s a1 = *(const v8s*)(xa + 16 * Dd + ks * 32);
        v8s w0 = *(const v8s*)(Bx0 + ks * 32);
        v8s w1 = *(const v8s*)(Bx1 + ks * 32);
        a00 = MFMA(a0, w0, a00);
        a01 = MFMA(a0, w1, a01);
        a10 = MFMA(a1, w0, a10);
        a11 = MFMA(a1, w1, a11);
      }
    }
    // ---- recurrent GEMM: K = 512 (skip at t=0, h=0)
    if (t > 0) {
      const u16* hc  = h_buf + (t & 1) * (Bb * Hh);
      const u16* ha0 = hc + arow * Hh + ko;
      const u16* ha1 = ha0 + 16 * Hh;
      #pragma unroll 4
      for (int ks = 0; ks < 16; ++ks) {
        v8s a0 = *(const v8s*)(ha0 + ks * 32);
        v8s a1 = *(const v8s*)(ha1 + ks * 32);
        v8s w0 = *(const v8s*)(Bh0 + ks * 32);
        v8s w1 = *(const v8s*)(Bh1 + ks * 32);
        a00 = MFMA(a0, w0, a00);
        a01 = MFMA(a0, w1, a01);
        a10 = MFMA(a1, w0, a10);
        a11 = MFMA(a1, w1, a11);
      }
    }

    // ---- stage gates to LDS: layout [col][row], C-frag row=(lane>>4)*4+reg
    {
      const int colb = wn0 + lm;
      const int rowb = wm0 + ((lane >> 4) << 2);
      *(v4f*)&gates[(colb     ) * GAT_S + rowb     ] = a00;
      *(v4f*)&gates[(colb + 16) * GAT_S + rowb     ] = a01;
      *(v4f*)&gates[(colb     ) * GAT_S + rowb + 16] = a10;
      *(v4f*)&gates[(colb + 16) * GAT_S + rowb + 16] = a11;
    }
    __syncthreads();

    // ---- c/h update: thread owns hidden unit (j0+jj) x 4 batches (b4..b4+3)
    {
      u16* hn = h_buf + ((t + 1) & 1) * (Bb * Hh);
      v4f iv = *(const v4f*)&gates[(jj     ) * GAT_S + b4];
      v4f fv = *(const v4f*)&gates[(16 + jj) * GAT_S + b4];
      v4f gv = *(const v4f*)&gates[(32 + jj) * GAT_S + b4];
      v4f ov = *(const v4f*)&gates[(48 + jj) * GAT_S + b4];

      float ig, fg, gg, og, hv;
      ig = sigm(iv[0] + bias[0]); fg = sigm(fv[0] + bias[1]);
      gg = tanh_f(gv[0] + bias[2]); og = sigm(ov[0] + bias[3]);
      cc0 = fg * cc0 + ig * gg; hv = og * tanh_f(cc0);
      hn[(b0 + b4 + 0) * Hh + j0 + jj] = f2bf(hv);

      ig = sigm(iv[1] + bias[0]); fg = sigm(fv[1] + bias[1]);
      gg = tanh_f(gv[1] + bias[2]); og = sigm(ov[1] + bias[3]);
      cc1 = fg * cc1 + ig * gg; hv = og * tanh_f(cc1);
      hn[(b0 + b4 + 1) * Hh + j0 + jj] = f2bf(hv);

      ig = sigm(iv[2] + bias[0]); fg = sigm(fv[2] + bias[1]);
      gg = tanh_f(gv[2] + bias[2]); og = sigm(ov[2] + bias[3]);
      cc2 = fg * cc2 + ig * gg; hv = og * tanh_f(cc2);
      hn[(b0 + b4 + 2) * Hh + j0 + jj] = f2bf(hv);

      ig = sigm(iv[3] + bias[0]); fg = sigm(fv[3] + bias[1]);
      gg = tanh_f(gv[3] + bias[2]); og = sigm(ov[3] + bias[3]);
      cc3 = fg * cc3 + ig * gg; hv = og * tanh_f(cc3);
      hn[(b0 + b4 + 3) * Hh + j0 + jj] = f2bf(hv);
    }

    // ---- publish h_{t+1}: drain stores (syncthreads), release, set flag
    __syncthreads();
    if (tid == 0) {
      __builtin_amdgcn_fence(__ATOMIC_RELEASE, "agent");
      __hip_atomic_store(&flags[fbase + chunk], (unsigned)(t + 1),
                         __ATOMIC_RELAXED, __HIP_MEMORY_SCOPE_AGENT);
    }
  }
}

// ---------------------------------------------------------------- epilogue:
// out[b] = h_last[b,:] . lin_w + lin_b   (h_last in h_buf[0], since T even)
__global__ void k_out(const u16* __restrict__ h, const float* __restrict__ lw,
                      const float* __restrict__ lb, float* __restrict__ out)
{
  int b = blockIdx.x * 64 + threadIdx.x;
  if (b >= Bb) return;
  const u16* hr = h + b * Hh;
  float acc = 0.f;
  #pragma unroll 8
  for (int k = 0; k < Hh; ++k) acc += bf2f(hr[k]) * lw[k];
  out[b] = acc + lb[0];
}

extern "C" void kernel_launch(void* const* d_in, const int* in_sizes, int n_in,
                              void* d_out, int out_size, void* d_ws, size_t ws_size,
                              hipStream_t stream)
{
  (void)in_sizes; (void)n_in; (void)out_size; (void)ws_size;
  const float* x       = (const float*)d_in[0];
  const float* wih_mu  = (const float*)d_in[1];
  const float* wih_rho = (const float*)d_in[2];
  const float* wih_eps = (const float*)d_in[3];
  const float* whh_mu  = (const float*)d_in[4];
  const float* whh_rho = (const float*)d_in[5];
  const float* whh_eps = (const float*)d_in[6];
  const float* b_mu    = (const float*)d_in[7];
  const float* b_rho   = (const float*)d_in[8];
  const float* b_eps   = (const float*)d_in[9];
  const float* lin_w   = (const float*)d_in[10];
  const float* lin_b   = (const float*)d_in[11];
  float* out = (float*)d_out;

  // workspace layout
  u16* x_bf  = (u16*)d_ws;                       // T*B*D bf16  = 16 MB
  u16* h_buf = x_bf + (size_t)Tt * Bb * Dd;      // 2*B*H bf16  = 512 KB
  unsigned* flags = (unsigned*)(h_buf + 2 * Bb * Hh);  // 128 uints

  k_prep<<<2048, 256, 0, stream>>>(x, x_bf, flags);

  hipFuncSetAttribute(reinterpret_cast<const void*>(lstm_main),
                      hipFuncAttributeMaxDynamicSharedMemorySize, SMEM_BYTES);
  lstm_main<<<NGROUP * NCHUNK, 256, SMEM_BYTES, stream>>>(
      whh_mu, whh_rho, whh_eps, wih_mu, wih_rho, wih_eps,
      b_mu, b_rho, b_eps, x_bf, h_buf, flags);

  k_out<<<(Bb + 63) / 64, 64, 0, stream>>>(h_buf, lin_w, lin_b, out);
}

// Round 2
// 5165.876 us; speedup vs baseline: 1.4084x; 1.4084x over previous
//
#include <hip/hip_runtime.h>

typedef unsigned short u16;
typedef unsigned long long u64;
typedef short v8s __attribute__((ext_vector_type(8)));
typedef float v4f __attribute__((ext_vector_type(4)));

#define Bb 256
#define Tt 512
#define Dd 64
#define Hh 512
#define G4 2048

#define NGROUP 4
#define NCHUNK 32
#define BT 64
#define HC 16
#define NCOL 64

#define WHH_S 520   // 512 + 8 pad (bf16 elems)
#define WIH_S 72    // 64 + 8 pad
#define GAT_S 68    // 64 + 4 pad (fp32 elems)
#define SMEM_BYTES (NCOL*WHH_S*2 + NCOL*WIH_S*2 + NCOL*GAT_S*4)  // 93184

#define MFMA(a,b,c) __builtin_amdgcn_mfma_f32_16x16x32_bf16((a),(b),(c),0,0,0)

__device__ __forceinline__ u16 f2bf(float f) {
  unsigned u = __float_as_uint(f);
  unsigned r = (u + 0x7fffu + ((u >> 16) & 1u)) >> 16;
  return (u16)r;
}
__device__ __forceinline__ float bf2f(u16 v) {
  return __uint_as_float(((unsigned)v) << 16);
}
__device__ __forceinline__ float sigm(float x) { return 1.0f / (1.0f + __expf(-x)); }
__device__ __forceinline__ float tanh_f(float x) {
  float a = fabsf(x);
  float e = __expf(-2.0f * a);
  float r = (1.0f - e) / (1.0f + e);
  return copysignf(r, x);
}
__device__ __forceinline__ float softplus_f(float x) { return log1pf(__expf(x)); }

// L3-coherent (L1+L2 bypass, sc0 sc1) 16B h-load as two 8B system atomics.
__device__ __forceinline__ v8s ld_h16(const u16* p) {
  union { u64 q[2]; v8s v; } u;
  u.q[0] = __hip_atomic_load((const u64*)p,       __ATOMIC_RELAXED, __HIP_MEMORY_SCOPE_SYSTEM);
  u.q[1] = __hip_atomic_load((const u64*)(p + 4), __ATOMIC_RELAXED, __HIP_MEMORY_SCOPE_SYSTEM);
  return u.v;
}

// ---------------------------------------------------------------- prep:
// x fp32 [B][T][D] -> bf16 [T][B][D]; zero sync flags.
__global__ void k_prep(const float* __restrict__ x, u16* __restrict__ x_bf,
                       unsigned* __restrict__ flags)
{
  if (blockIdx.x == 0 && threadIdx.x < NGROUP * NCHUNK) flags[threadIdx.x] = 0u;
  const int N4 = Tt * Bb * Dd / 4;
  int stride = gridDim.x * blockDim.x;
  for (int i = blockIdx.x * blockDim.x + threadIdx.x; i < N4; i += stride) {
    int idx = i * 4;
    int t = idx >> 14;          // / (B*D)
    int rem = idx & 16383;
    int b = rem >> 6;
    int d = rem & 63;
    float4 v = *(const float4*)(x + (size_t)b * (Tt * Dd) + t * Dd + d);
    unsigned lo = (unsigned)f2bf(v.x) | ((unsigned)f2bf(v.y) << 16);
    unsigned hi = (unsigned)f2bf(v.z) | ((unsigned)f2bf(v.w) << 16);
    *(uint2*)(x_bf + idx) = make_uint2(lo, hi);
  }
}

// ---------------------------------------------------------------- main:
// persistent LSTM. grid = 128 blocks (4 batch groups x 32 hidden chunks),
// 256 threads. w_hh/w_ih chunk sampled into LDS once; 512 steps with
// flag-based producer/consumer sync per batch group. All h exchange goes
// through L3 (sc0 sc1) -> NO agent fences / L2 wb/inv on the critical path.
__global__ __launch_bounds__(256, 1) void lstm_main(
    const float* __restrict__ whh_mu, const float* __restrict__ whh_rho, const float* __restrict__ whh_eps,
    const float* __restrict__ wih_mu, const float* __restrict__ wih_rho, const float* __restrict__ wih_eps,
    const float* __restrict__ b_mu,  const float* __restrict__ b_rho,  const float* __restrict__ b_eps,
    const u16* __restrict__ x_bf, u16* __restrict__ h_buf, unsigned* __restrict__ flags)
{
  extern __shared__ char smem[];
  u16*   w_hh_lds = (u16*)smem;                       // [NCOL][WHH_S]
  u16*   w_ih_lds = w_hh_lds + NCOL * WHH_S;          // [NCOL][WIH_S]
  float* gates    = (float*)(w_ih_lds + NCOL * WIH_S);// [NCOL][GAT_S]

  const int tid   = threadIdx.x;
  const int g     = blockIdx.x & 3;    // batch group
  const int chunk = blockIdx.x >> 2;   // hidden chunk
  const int b0    = g * BT;
  const int j0    = chunk * HC;

  // ---- sample weight chunk into LDS (bf16). local col lc = gate*16 + jj
  {
    const int lc = tid & 63;
    const int gcol = (lc >> 4) * Hh + j0 + (lc & 15);  // global gate column
    for (int k = tid >> 6; k < Hh; k += 4) {
      int gi = k * G4 + gcol;
      float w = whh_mu[gi] + softplus_f(whh_rho[gi]) * whh_eps[gi];
      w_hh_lds[lc * WHH_S + k] = f2bf(w);
    }
    for (int k = tid >> 6; k < Dd; k += 4) {
      int gi = k * G4 + gcol;
      float w = wih_mu[gi] + softplus_f(wih_rho[gi]) * wih_eps[gi];
      w_ih_lds[lc * WIH_S + k] = f2bf(w);
    }
  }

  // ---- c/h-update mapping: thread owns batch ub x 4 units (jg*4..jg*4+3)
  const int ub = tid >> 2;     // batch within group, 0..63
  const int jg = tid & 3;      // unit quad, 0..3
  float bias[4][4];            // [gate][u]
  #pragma unroll
  for (int gt = 0; gt < 4; ++gt)
    #pragma unroll
    for (int u = 0; u < 4; ++u) {
      int colg = gt * Hh + j0 + jg * 4 + u;
      bias[gt][u] = b_mu[colg] + softplus_f(b_rho[colg]) * b_eps[colg];
    }
  __syncthreads();

  // ---- MFMA geometry: 4 waves tile the 64x64 gate tile as 2x2 of 32x32
  const int lane = tid & 63;
  const int wv   = tid >> 6;
  const int wm0  = (wv & 1) * 32;
  const int wn0  = (wv >> 1) * 32;
  const int lm   = lane & 15;
  const int ko   = (lane >> 4) * 8;

  const u16* Bh0 = w_hh_lds + (wn0 + lm) * WHH_S + ko;
  const u16* Bh1 = Bh0 + 16 * WHH_S;
  const u16* Bx0 = w_ih_lds + (wn0 + lm) * WIH_S + ko;
  const u16* Bx1 = Bx0 + 16 * WIH_S;

  const int arow = b0 + wm0 + lm;   // A-fragment row in global h / x

  float cc[4] = {0.f, 0.f, 0.f, 0.f};   // persistent cell state
  const int fbase = g * NCHUNK;

  for (int t = 0; t < Tt; ++t) {
    v4f a00 = {0.f, 0.f, 0.f, 0.f};
    v4f a01 = {0.f, 0.f, 0.f, 0.f};
    v4f a10 = {0.f, 0.f, 0.f, 0.f};
    v4f a11 = {0.f, 0.f, 0.f, 0.f};

    // ---- input projection first: h-independent, overlaps the flag wait
    {
      const u16* xa = x_bf + (size_t)t * (Bb * Dd) + arow * Dd + ko;
      #pragma unroll
      for (int ks = 0; ks < 2; ++ks) {
        v8s a0 = *(const v8s*)(xa + ks * 32);
        v8s a1 = *(const v8s*)(xa + 16 * Dd + ks * 32);
        v8s w0 = *(const v8s*)(Bx0 + ks * 32);
        v8s w1 = *(const v8s*)(Bx1 + ks * 32);
        a00 = MFMA(a0, w0, a00);
        a01 = MFMA(a0, w1, a01);
        a10 = MFMA(a1, w0, a10);
        a11 = MFMA(a1, w1, a11);
      }
    }

    // ---- wait until all chunks of this group published h_t (L3 polls)
    if (t > 0) {
      if (tid < NCHUNK) {
        while (__hip_atomic_load(&flags[fbase + tid], __ATOMIC_RELAXED,
                                 __HIP_MEMORY_SCOPE_SYSTEM) < (unsigned)t) { }
      }
      __syncthreads();

      // ---- recurrent GEMM: K = 512, A fragments direct from L3
      const u16* hc  = h_buf + (t & 1) * (Bb * Hh);
      const u16* ha0 = hc + arow * Hh + ko;
      const u16* ha1 = ha0 + 16 * Hh;
      #pragma unroll 4
      for (int ks = 0; ks < 16; ++ks) {
        v8s a0 = ld_h16(ha0 + ks * 32);
        v8s a1 = ld_h16(ha1 + ks * 32);
        v8s w0 = *(const v8s*)(Bh0 + ks * 32);
        v8s w1 = *(const v8s*)(Bh1 + ks * 32);
        a00 = MFMA(a0, w0, a00);
        a01 = MFMA(a0, w1, a01);
        a10 = MFMA(a1, w0, a10);
        a11 = MFMA(a1, w1, a11);
      }
    }

    // ---- stage gates to LDS: layout [col][row], C-frag row=(lane>>4)*4+reg
    {
      const int colb = wn0 + lm;
      const int rowb = wm0 + ((lane >> 4) << 2);
      *(v4f*)&gates[(colb     ) * GAT_S + rowb     ] = a00;
      *(v4f*)&gates[(colb + 16) * GAT_S + rowb     ] = a01;
      *(v4f*)&gates[(colb     ) * GAT_S + rowb + 16] = a10;
      *(v4f*)&gates[(colb + 16) * GAT_S + rowb + 16] = a11;
    }
    __syncthreads();

    // ---- c/h update: thread owns batch ub x units jg*4..jg*4+3
    {
      u16* hn = h_buf + ((t + 1) & 1) * (Bb * Hh);
      unsigned hv2[2];
      u16* hv = (u16*)hv2;
      #pragma unroll
      for (int u = 0; u < 4; ++u) {
        int j = jg * 4 + u;
        float iv = gates[(      j) * GAT_S + ub];
        float fv = gates[(16 + j) * GAT_S + ub];
        float gv = gates[(32 + j) * GAT_S + ub];
        float ov = gates[(48 + j) * GAT_S + ub];
        float ig = sigm(iv + bias[0][u]);
        float fg = sigm(fv + bias[1][u]);
        float gg = tanh_f(gv + bias[2][u]);
        float og = sigm(ov + bias[3][u]);
        cc[u] = fg * cc[u] + ig * gg;
        hv[u] = f2bf(og * tanh_f(cc[u]));
      }
      // one contiguous 8B write-through (sc0 sc1) store: 4 bf16
      u64 q = (u64)hv2[0] | ((u64)hv2[1] << 32);
      __hip_atomic_store((u64*)&hn[(b0 + ub) * Hh + j0 + jg * 4], q,
                         __ATOMIC_RELAXED, __HIP_MEMORY_SCOPE_SYSTEM);
    }

    // ---- publish: wait store-ack (per-wave), join waves, set flag (L3)
    asm volatile("s_waitcnt vmcnt(0)" ::: "memory");
    __syncthreads();
    if (tid == 0) {
      __hip_atomic_store(&flags[fbase + chunk], (unsigned)(t + 1),
                         __ATOMIC_RELAXED, __HIP_MEMORY_SCOPE_SYSTEM);
    }
  }
}

// ---------------------------------------------------------------- epilogue:
// out[b] = h_last[b,:] . lin_w + lin_b   (h_last in h_buf[0], since T even)
__global__ void k_out(const u16* __restrict__ h, const float* __restrict__ lw,
                      const float* __restrict__ lb, float* __restrict__ out)
{
  int b = blockIdx.x * 64 + threadIdx.x;
  if (b >= Bb) return;
  const u16* hr = h + b * Hh;
  float acc = 0.f;
  #pragma unroll 8
  for (int k = 0; k < Hh; ++k) acc += bf2f(hr[k]) * lw[k];
  out[b] = acc + lb[0];
}

extern "C" void kernel_launch(void* const* d_in, const int* in_sizes, int n_in,
                              void* d_out, int out_size, void* d_ws, size_t ws_size,
                              hipStream_t stream)
{
  (void)in_sizes; (void)n_in; (void)out_size; (void)ws_size;
  const float* x       = (const float*)d_in[0];
  const float* wih_mu  = (const float*)d_in[1];
  const float* wih_rho = (const float*)d_in[2];
  const float* wih_eps = (const float*)d_in[3];
  const float* whh_mu  = (const float*)d_in[4];
  const float* whh_rho = (const float*)d_in[5];
  const float* whh_eps = (const float*)d_in[6];
  const float* b_mu    = (const float*)d_in[7];
  const float* b_rho   = (const float*)d_in[8];
  const float* b_eps   = (const float*)d_in[9];
  const float* lin_w   = (const float*)d_in[10];
  const float* lin_b   = (const float*)d_in[11];
  float* out = (float*)d_out;

  // workspace layout
  u16* x_bf  = (u16*)d_ws;                       // T*B*D bf16  = 16 MB
  u16* h_buf = x_bf + (size_t)Tt * Bb * Dd;      // 2*B*H bf16  = 512 KB
  unsigned* flags = (unsigned*)(h_buf + 2 * Bb * Hh);  // 128 uints

  k_prep<<<2048, 256, 0, stream>>>(x, x_bf, flags);

  hipFuncSetAttribute(reinterpret_cast<const void*>(lstm_main),
                      hipFuncAttributeMaxDynamicSharedMemorySize, SMEM_BYTES);
  lstm_main<<<NGROUP * NCHUNK, 256, SMEM_BYTES, stream>>>(
      whh_mu, whh_rho, whh_eps, wih_mu, wih_rho, wih_eps,
      b_mu, b_rho, b_eps, x_bf, h_buf, flags);

  k_out<<<(Bb + 63) / 64, 64, 0, stream>>>(h_buf, lin_w, lin_b, out);
}

// Round 3
// 3537.614 us; speedup vs baseline: 2.0567x; 1.4603x over previous
//
#include <hip/hip_runtime.h>

typedef unsigned short u16;
typedef unsigned long long u64;
typedef short v8s __attribute__((ext_vector_type(8)));
typedef float v4f __attribute__((ext_vector_type(4)));

#define Bb 256
#define Tt 512
#define Dd 64
#define Hh 512
#define G4 2048

#define NGROUP 4
#define NCHUNK 32
#define BT 64
#define HC 16
#define NCOL 64

#define WHH_S 520   // 512 + 8 pad (bf16 elems)
#define WIH_S 72    // 64 + 8 pad
#define GAT_S 68    // 64 + 4 pad (fp32 elems)
#define SMEM_BYTES (NCOL*WHH_S*2 + NCOL*WIH_S*2 + NCOL*GAT_S*4)  // 93184

#define MFMA(a,b,c) __builtin_amdgcn_mfma_f32_16x16x32_bf16((a),(b),(c),0,0,0)

__device__ __forceinline__ u16 f2bf(float f) {
  unsigned u = __float_as_uint(f);
  unsigned r = (u + 0x7fffu + ((u >> 16) & 1u)) >> 16;
  return (u16)r;
}
__device__ __forceinline__ float bf2f(u16 v) {
  return __uint_as_float(((unsigned)v) << 16);
}
__device__ __forceinline__ float sigm(float x) { return 1.0f / (1.0f + __expf(-x)); }
__device__ __forceinline__ float tanh_f(float x) {
  float a = fabsf(x);
  float e = __expf(-2.0f * a);
  float r = (1.0f - e) / (1.0f + e);
  return copysignf(r, x);
}
__device__ __forceinline__ float softplus_f(float x) { return log1pf(__expf(x)); }

// ---------------------------------------------------------------- prep:
// x fp32 [B][T][D] -> bf16 [T][B][D]; zero sync flags.
__global__ void k_prep(const float* __restrict__ x, u16* __restrict__ x_bf,
                       unsigned* __restrict__ flags)
{
  if (blockIdx.x == 0 && threadIdx.x < NGROUP * NCHUNK) flags[threadIdx.x] = 0u;
  const int N4 = Tt * Bb * Dd / 4;
  int stride = gridDim.x * blockDim.x;
  for (int i = blockIdx.x * blockDim.x + threadIdx.x; i < N4; i += stride) {
    int idx = i * 4;
    int t = idx >> 14;          // / (B*D)
    int rem = idx & 16383;
    int b = rem >> 6;
    int d = rem & 63;
    float4 v = *(const float4*)(x + (size_t)b * (Tt * Dd) + t * Dd + d);
    unsigned lo = (unsigned)f2bf(v.x) | ((unsigned)f2bf(v.y) << 16);
    unsigned hi = (unsigned)f2bf(v.z) | ((unsigned)f2bf(v.w) << 16);
    *(uint2*)(x_bf + idx) = make_uint2(lo, hi);
  }
}

// ---------------------------------------------------------------- main:
// persistent LSTM. grid = 128 blocks (4 batch groups x 32 hidden chunks),
// 256 threads. w_hh/w_ih chunk sampled into LDS once; 512 steps with
// flag-based producer/consumer sync per batch group. h exchange via L3
// (sc0 sc1 raw loads/stores) -> no fences, and loads are fully pipelined
// (32 in flight, ONE vmcnt drain) instead of per-atomic serialization.
__global__ __launch_bounds__(256, 1) void lstm_main(
    const float* __restrict__ whh_mu, const float* __restrict__ whh_rho, const float* __restrict__ whh_eps,
    const float* __restrict__ wih_mu, const float* __restrict__ wih_rho, const float* __restrict__ wih_eps,
    const float* __restrict__ b_mu,  const float* __restrict__ b_rho,  const float* __restrict__ b_eps,
    const u16* __restrict__ x_bf, u16* __restrict__ h_buf, unsigned* __restrict__ flags)
{
  extern __shared__ char smem[];
  u16*   w_hh_lds = (u16*)smem;                       // [NCOL][WHH_S]
  u16*   w_ih_lds = w_hh_lds + NCOL * WHH_S;          // [NCOL][WIH_S]
  float* gates    = (float*)(w_ih_lds + NCOL * WIH_S);// [NCOL][GAT_S]

  const int tid   = threadIdx.x;
  const int g     = blockIdx.x & 3;    // batch group
  const int chunk = blockIdx.x >> 2;   // hidden chunk
  const int b0    = g * BT;
  const int j0    = chunk * HC;

  // ---- sample weight chunk into LDS (bf16). local col lc = gate*16 + jj
  {
    const int lc = tid & 63;
    const int gcol = (lc >> 4) * Hh + j0 + (lc & 15);  // global gate column
    for (int k = tid >> 6; k < Hh; k += 4) {
      int gi = k * G4 + gcol;
      float w = whh_mu[gi] + softplus_f(whh_rho[gi]) * whh_eps[gi];
      w_hh_lds[lc * WHH_S + k] = f2bf(w);
    }
    for (int k = tid >> 6; k < Dd; k += 4) {
      int gi = k * G4 + gcol;
      float w = wih_mu[gi] + softplus_f(wih_rho[gi]) * wih_eps[gi];
      w_ih_lds[lc * WIH_S + k] = f2bf(w);
    }
  }

  // ---- c/h-update mapping: thread owns batch ub x 4 units (jg*4..jg*4+3)
  const int ub = tid >> 2;     // batch within group, 0..63
  const int jg = tid & 3;      // unit quad, 0..3
  float bias[4][4];            // [gate][u]
  #pragma unroll
  for (int gt = 0; gt < 4; ++gt)
    #pragma unroll
    for (int u = 0; u < 4; ++u) {
      int colg = gt * Hh + j0 + jg * 4 + u;
      bias[gt][u] = b_mu[colg] + softplus_f(b_rho[colg]) * b_eps[colg];
    }
  __syncthreads();

  // ---- MFMA geometry: 4 waves tile the 64x64 gate tile as 2x2 of 32x32
  const int lane = tid & 63;
  const int wv   = tid >> 6;
  const int wm0  = (wv & 1) * 32;
  const int wn0  = (wv >> 1) * 32;
  const int lm   = lane & 15;
  const int ko   = (lane >> 4) * 8;

  const u16* Bh0 = w_hh_lds + (wn0 + lm) * WHH_S + ko;
  const u16* Bh1 = Bh0 + 16 * WHH_S;
  const u16* Bx0 = w_ih_lds + (wn0 + lm) * WIH_S + ko;
  const u16* Bx1 = Bx0 + 16 * WIH_S;

  const int arow = b0 + wm0 + lm;   // A-fragment row in global h / x

  float cc[4] = {0.f, 0.f, 0.f, 0.f};   // persistent cell state
  const int fbase = g * NCHUNK;

  for (int t = 0; t < Tt; ++t) {
    v4f a00 = {0.f, 0.f, 0.f, 0.f};
    v4f a01 = {0.f, 0.f, 0.f, 0.f};
    v4f a10 = {0.f, 0.f, 0.f, 0.f};
    v4f a11 = {0.f, 0.f, 0.f, 0.f};

    // ---- input projection first: h-independent, overlaps the flag wait
    {
      const u16* xa = x_bf + (size_t)t * (Bb * Dd) + arow * Dd + ko;
      #pragma unroll
      for (int ks = 0; ks < 2; ++ks) {
        v8s a0 = *(const v8s*)(xa + ks * 32);
        v8s a1 = *(const v8s*)(xa + 16 * Dd + ks * 32);
        v8s w0 = *(const v8s*)(Bx0 + ks * 32);
        v8s w1 = *(const v8s*)(Bx1 + ks * 32);
        a00 = MFMA(a0, w0, a00);
        a01 = MFMA(a0, w1, a01);
        a10 = MFMA(a1, w0, a10);
        a11 = MFMA(a1, w1, a11);
      }
    }

    // ---- wait until all chunks of this group published h_t (L3 polls)
    if (t > 0) {
      if (tid < NCHUNK) {
        while (__hip_atomic_load(&flags[fbase + tid], __ATOMIC_RELAXED,
                                 __HIP_MEMORY_SCOPE_SYSTEM) < (unsigned)t) { }
      }
      __syncthreads();

      // ---- recurrent GEMM: K = 512. Issue ALL 32 coherent loads (sc0 sc1
      // bypass L1/L2 -> read L3, where producers wrote through), then one
      // vmcnt(0) drain, then 64 MFMAs. No per-load serialization.
      const u16* hc  = h_buf + (t & 1) * (Bb * Hh);
      const u16* ha0 = hc + arow * Hh + ko;
      const u16* ha1 = ha0 + 16 * Hh;
      v8s A0[16], A1[16];
      #pragma unroll
      for (int ks = 0; ks < 16; ++ks) {
        asm volatile("global_load_dwordx4 %0, %1, off offset:%c2 sc0 sc1"
                     : "=v"(A0[ks]) : "v"(ha0), "i"(ks * 64));
        asm volatile("global_load_dwordx4 %0, %1, off offset:%c2 sc0 sc1"
                     : "=v"(A1[ks]) : "v"(ha1), "i"(ks * 64));
      }
      asm volatile("s_waitcnt vmcnt(0)" ::: "memory");
      // pin ordering: redefine A regs AFTER the drain so the scheduler
      // cannot hoist dependent MFMAs above the waitcnt.
      #pragma unroll
      for (int ks = 0; ks < 16; ++ks) {
        asm volatile("" : "+v"(A0[ks]), "+v"(A1[ks]));
      }
      #pragma unroll
      for (int ks = 0; ks < 16; ++ks) {
        v8s w0 = *(const v8s*)(Bh0 + ks * 32);
        v8s w1 = *(const v8s*)(Bh1 + ks * 32);
        a00 = MFMA(A0[ks], w0, a00);
        a01 = MFMA(A0[ks], w1, a01);
        a10 = MFMA(A1[ks], w0, a10);
        a11 = MFMA(A1[ks], w1, a11);
      }
    }

    // ---- stage gates to LDS: layout [col][row], C-frag row=(lane>>4)*4+reg
    {
      const int colb = wn0 + lm;
      const int rowb = wm0 + ((lane >> 4) << 2);
      *(v4f*)&gates[(colb     ) * GAT_S + rowb     ] = a00;
      *(v4f*)&gates[(colb + 16) * GAT_S + rowb     ] = a01;
      *(v4f*)&gates[(colb     ) * GAT_S + rowb + 16] = a10;
      *(v4f*)&gates[(colb + 16) * GAT_S + rowb + 16] = a11;
    }
    __syncthreads();

    // ---- c/h update: thread owns batch ub x units jg*4..jg*4+3
    {
      u16* hn = h_buf + ((t + 1) & 1) * (Bb * Hh);
      unsigned hv2[2];
      u16* hv = (u16*)hv2;
      #pragma unroll
      for (int u = 0; u < 4; ++u) {
        int j = jg * 4 + u;
        float iv = gates[(      j) * GAT_S + ub];
        float fv = gates[(16 + j) * GAT_S + ub];
        float gv = gates[(32 + j) * GAT_S + ub];
        float ov = gates[(48 + j) * GAT_S + ub];
        float ig = sigm(iv + bias[0][u]);
        float fg = sigm(fv + bias[1][u]);
        float gg = tanh_f(gv + bias[2][u]);
        float og = sigm(ov + bias[3][u]);
        cc[u] = fg * cc[u] + ig * gg;
        hv[u] = f2bf(og * tanh_f(cc[u]));
      }
      // one contiguous 8B write-through (sc0 sc1) store: 4 bf16
      u64 q = (u64)hv2[0] | ((u64)hv2[1] << 32);
      __hip_atomic_store((u64*)&hn[(b0 + ub) * Hh + j0 + jg * 4], q,
                         __ATOMIC_RELAXED, __HIP_MEMORY_SCOPE_SYSTEM);
    }

    // ---- publish: wait store-ack (per-wave), join waves, set flag (L3)
    asm volatile("s_waitcnt vmcnt(0)" ::: "memory");
    __syncthreads();
    if (tid == 0) {
      __hip_atomic_store(&flags[fbase + chunk], (unsigned)(t + 1),
                         __ATOMIC_RELAXED, __HIP_MEMORY_SCOPE_SYSTEM);
    }
  }
}

// ---------------------------------------------------------------- epilogue:
// out[b] = h_last[b,:] . lin_w + lin_b   (h_last in h_buf[0], since T even)
__global__ void k_out(const u16* __restrict__ h, const float* __restrict__ lw,
                      const float* __restrict__ lb, float* __restrict__ out)
{
  int b = blockIdx.x * 64 + threadIdx.x;
  if (b >= Bb) return;
  const u16* hr = h + b * Hh;
  float acc = 0.f;
  #pragma unroll 8
  for (int k = 0; k < Hh; ++k) acc += bf2f(hr[k]) * lw[k];
  out[b] = acc + lb[0];
}

extern "C" void kernel_launch(void* const* d_in, const int* in_sizes, int n_in,
                              void* d_out, int out_size, void* d_ws, size_t ws_size,
                              hipStream_t stream)
{
  (void)in_sizes; (void)n_in; (void)out_size; (void)ws_size;
  const float* x       = (const float*)d_in[0];
  const float* wih_mu  = (const float*)d_in[1];
  const float* wih_rho = (const float*)d_in[2];
  const float* wih_eps = (const float*)d_in[3];
  const float* whh_mu  = (const float*)d_in[4];
  const float* whh_rho = (const float*)d_in[5];
  const float* whh_eps = (const float*)d_in[6];
  const float* b_mu    = (const float*)d_in[7];
  const float* b_rho   = (const float*)d_in[8];
  const float* b_eps   = (const float*)d_in[9];
  const float* lin_w   = (const float*)d_in[10];
  const float* lin_b   = (const float*)d_in[11];
  float* out = (float*)d_out;

  // workspace layout
  u16* x_bf  = (u16*)d_ws;                       // T*B*D bf16  = 16 MB
  u16* h_buf = x_bf + (size_t)Tt * Bb * Dd;      // 2*B*H bf16  = 512 KB
  unsigned* flags = (unsigned*)(h_buf + 2 * Bb * Hh);  // 128 uints

  k_prep<<<2048, 256, 0, stream>>>(x, x_bf, flags);

  hipFuncSetAttribute(reinterpret_cast<const void*>(lstm_main),
                      hipFuncAttributeMaxDynamicSharedMemorySize, SMEM_BYTES);
  lstm_main<<<NGROUP * NCHUNK, 256, SMEM_BYTES, stream>>>(
      whh_mu, whh_rho, whh_eps, wih_mu, wih_rho, wih_eps,
      b_mu, b_rho, b_eps, x_bf, h_buf, flags);

  k_out<<<(Bb + 63) / 64, 64, 0, stream>>>(h_buf, lin_w, lin_b, out);
}